// Round 4
// baseline (360.214 us; speedup 1.0000x reference)
//
#include <hip/hip_runtime.h>
#include <stdint.h>

typedef __attribute__((ext_vector_type(8))) short bf16x8;
typedef __attribute__((ext_vector_type(4))) float f32x4;
typedef unsigned long long ull;

// ---- LDS layout (bytes), total 38992 -> 4 blocks/CU (155968 <= 163840) ----
#define OFF_ACT  0        // [256][64] bf16, stride 128B, swz off128()  (h / cin / c1 / c2)
#define OFF_WC0  32768    // [64][32] bf16 (k-permuted: col0 dead, 1..15=dc, 16..31=SH), 64B stride
#define OFF_OUT4 36864    // [256] x 4 bf16  (sigma, r, g, b) packed u64
#define OFF_SHB  38912    // [2][16] u16 (bf16 SH coeffs)
#define OFF_WTOT 38976    // [4] int
#define SMEM_BYTES 38992

__device__ __forceinline__ unsigned short f2bf(float f) {
    unsigned int u = __float_as_uint(f);
    unsigned int r = (u + 0x7FFFu + ((u >> 16) & 1u)) >> 16;   // RNE
    return (unsigned short)r;
}

__device__ __forceinline__ bf16x8 pack8(float4 a, float4 b) {
    bf16x8 r;
    r[0] = (short)f2bf(a.x); r[1] = (short)f2bf(a.y);
    r[2] = (short)f2bf(a.z); r[3] = (short)f2bf(a.w);
    r[4] = (short)f2bf(b.x); r[5] = (short)f2bf(b.y);
    r[6] = (short)f2bf(b.z); r[7] = (short)f2bf(b.w);
    return r;
}

__device__ __forceinline__ ull pk4(float a, float b, float c, float d) {
    return (ull)f2bf(a) | ((ull)f2bf(b) << 16) | ((ull)f2bf(c) << 32) | ((ull)f2bf(d) << 48);
}
__device__ __forceinline__ ull pk4r(f32x4 v) {  // relu + pack
    return pk4(fmaxf(v[0], 0.f), fmaxf(v[1], 0.f), fmaxf(v[2], 0.f), fmaxf(v[3], 0.f));
}

// 128B-stride ACT: slot = (row&7) ^ (bit3(row)<<1); b128 reads 2-way (free), b64 D-writes <=4-way
__device__ __forceinline__ int off128(int row, int col) {
    int off = row * 128 + col * 2;
    return off ^ ((((row & 7) ^ ((row >> 2) & 2))) << 4);
}
// 64B-stride WC0: ^(((row>>1)&3)<<4) -> <=2-way (free)
__device__ __forceinline__ bf16x8 ldf32(const char* base, int row, int k0) {
    int off = row * 64 + k0 * 2;
    off ^= ((row >> 1) & 3) << 4;
    return *(const bf16x8*)(base + off);
}
__device__ __forceinline__ bf16x8 ldf64(const char* base, int row, int k0) {
    return *(const bf16x8*)(base + off128(row, k0));
}

// Probe: mask int32 vs bool bytes (ray 0 has exactly 128 valid).
__global__ void __launch_bounds__(64) detect_mask_kernel(const int* __restrict__ m, int* __restrict__ flag) {
    int l = threadIdx.x;
    unsigned long long s = 0;
    #pragma unroll
    for (int i = 0; i < 8; ++i) s += (unsigned long long)(unsigned int)m[l + i * 64];
    #pragma unroll
    for (int d = 32; d >= 1; d >>= 1) s += __shfl_down(s, d, 64);
    if (l == 0) *flag = (s == 128ull) ? 1 : 0;
}

__global__ void __launch_bounds__(256, 4) nnrender_main(
    const float* __restrict__ df, const void* __restrict__ maskp, const float* __restrict__ rays,
    const float* __restrict__ Ws0, const float* __restrict__ Ws1, const float* __restrict__ Wc0,
    const float* __restrict__ Wc1, const float* __restrict__ Wc2,
    float* __restrict__ out, const int* __restrict__ flagp) {

    __shared__ __align__(16) char smem[SMEM_BYTES];
    const int tid = threadIdx.x;
    const int w = tid >> 6;           // wave 0..3, owns sample rows [64w, 64w+64)
    const int l = tid & 63;
    const int q = l & 15;
    const int h8 = (l >> 4) << 3;     // k-chunk base
    const int h4 = (l >> 4) << 2;     // D feature-group base (swapped layout)
    const int blk = blockIdx.x;
    const int b0 = blk * 2;

    char* ACT = smem + OFF_ACT;
    const int use_i32 = *flagp;

    // ---- phase 0: all operand loads from global; WC0 staged (k-permuted); SH; mask scan ----
    // df B-frags (samples): lane q=sample row, k=h8..h8+7
    bf16x8 dfr[4];
    {
        const float* p0 = df + ((size_t)(blk * 256 + w * 64 + q)) * 32 + h8;
        #pragma unroll
        for (int m = 0; m < 4; ++m) {
            const float* p = p0 + m * 16 * 32;
            dfr[m] = pack8(*(const float4*)p, *(const float4*)(p + 4));
        }
    }
    // W0 A-frags: Ws0[n*16+q][h8..h8+7]
    bf16x8 bW0[4];
    #pragma unroll
    for (int n = 0; n < 4; ++n) {
        const float* p = Ws0 + (n * 16 + q) * 32 + h8;
        bW0[n] = pack8(*(const float4*)p, *(const float4*)(p + 4));
    }
    // W1 A-frags (16 out-features), W2 A-frags (3 real rows, dup row 0 elsewhere)
    bf16x8 bW1[2], bW2[2];
    {
        const float* p1 = Ws1 + q * 64 + h8;
        bW1[0] = pack8(*(const float4*)p1, *(const float4*)(p1 + 4));
        bW1[1] = pack8(*(const float4*)(p1 + 32), *(const float4*)(p1 + 36));
        int qc = (q < 3) ? q : 0;
        const float* p2 = Wc2 + qc * 64 + h8;
        bW2[0] = pack8(*(const float4*)p2, *(const float4*)(p2 + 4));
        bW2[1] = pack8(*(const float4*)(p2 + 32), *(const float4*)(p2 + 36));
    }
    // Wc1 A-frags: Wc1[n*16+q][kk*32+h8 ..]
    bf16x8 bWc1[4][2];
    #pragma unroll
    for (int n = 0; n < 4; ++n) {
        const float* p = Wc1 + (n * 16 + q) * 64 + h8;
        bWc1[n][0] = pack8(*(const float4*)p, *(const float4*)(p + 4));
        bWc1[n][1] = pack8(*(const float4*)(p + 32), *(const float4*)(p + 36));
    }

    // mask load: thread covers 4 consecutive slots; waves 0,1 -> ray b0; 2,3 -> ray b0+1
    unsigned int mb[4];
    {
        size_t base = (size_t)b0 * 512 + tid * 4;
        if (use_i32) {
            int4 mv = *(const int4*)((const int*)maskp + base);
            mb[0] = mv.x != 0; mb[1] = mv.y != 0; mb[2] = mv.z != 0; mb[3] = mv.w != 0;
        } else {
            unsigned int u = *(const unsigned int*)((const unsigned char*)maskp + base);
            mb[0] = (u & 0xFFu) != 0; mb[1] = ((u >> 8) & 0xFFu) != 0;
            mb[2] = ((u >> 16) & 0xFFu) != 0; mb[3] = (u >> 24) != 0;
        }
    }

    // stage WC0 with permuted k: col0=0 (dead), cols1..15 = Wc0[:,16..30] (dc), cols16..31 = Wc0[:,0..15] (SH)
    for (int i = tid; i < 2048; i += 256) {
        int n = i >> 5, k = i & 31;
        float v;
        if (k == 0) v = 0.f;
        else if (k < 16) v = Wc0[n * 31 + 15 + k];
        else v = Wc0[n * 31 + (k - 16)];
        int off = i * 2 ^ (((n >> 1) & 3) << 4);
        *(unsigned short*)(smem + OFF_WC0 + off) = f2bf(v);
    }

    if (tid < 2) {  // SH deg-4 (16 coeffs) for this block's 2 rays
        const float* rd = rays + (size_t)(b0 + tid) * 3;
        float x = rd[0], y = rd[1], z = rd[2];
        float x2 = x * x, y2 = y * y, z2 = z * z, xy = x * y, yz = y * z, xz = x * z;
        float s[16];
        s[0] = 0.28209479177387814f;
        s[1] = -0.48860251190291987f * y;
        s[2] =  0.48860251190291987f * z;
        s[3] = -0.48860251190291987f * x;
        s[4] =  1.0925484305920792f * xy;
        s[5] = -1.0925484305920792f * yz;
        s[6] =  0.94617469575755997f * z2 - 0.31539156525251999f;
        s[7] = -1.0925484305920792f * xz;
        s[8] =  0.54627421529603959f * (x2 - y2);
        s[9] =  0.59004358992664352f * y * (-3.0f * x2 + y2);
        s[10] = 2.8906114426405538f * xy * z;
        s[11] = 0.45704579946446572f * y * (1.0f - 5.0f * z2);
        s[12] = 0.3731763325901154f * z * (5.0f * z2 - 3.0f);
        s[13] = 0.45704579946446572f * x * (1.0f - 5.0f * z2);
        s[14] = 1.445305721320277f * z * (x2 - y2);
        s[15] = 0.59004358992664352f * x * (-x2 + 3.0f * y2);
        unsigned short* d = (unsigned short*)(smem + OFF_SHB) + tid * 16;
        #pragma unroll
        for (int i = 0; i < 16; ++i) d[i] = f2bf(s[i]);
    }

    // wave-wide inclusive scan of per-thread valid count
    int c = (int)(mb[0] + mb[1] + mb[2] + mb[3]);
    int incl = c;
    #pragma unroll
    for (int d = 1; d < 64; d <<= 1) {
        int v = __shfl_up(incl, d, 64);
        if (l >= d) incl += v;
    }
    if (l == 63) ((int*)(smem + OFF_WTOT))[w] = incl;

    __syncthreads();   // ---- barrier 1 ----

    int rank0;
    {
        int base = (w & 1) ? ((int*)(smem + OFF_WTOT))[w - 1] : 0;
        rank0 = base + incl - c;
    }

    // ---- GEMM1 (swapped): D = (df @ Ws0^T)^T; lane holds feats n*16+h4..+3 of sample w*64+m*16+q ----
    #pragma unroll
    for (int m = 0; m < 4; ++m) {
        int s = w * 64 + m * 16 + q;
        #pragma unroll
        for (int n = 0; n < 4; ++n) {
            f32x4 acc = {0.f, 0.f, 0.f, 0.f};
            acc = __builtin_amdgcn_mfma_f32_16x16x32_bf16(bW0[n], dfr[m], acc, 0, 0, 0);
            *(ull*)(ACT + off128(s, n * 16 + h4)) = pk4r(acc);
        }
    }

    // ---- GEMM2 (swapped): dc = h @ Ws1^T; feats h4..h4+3 of sample -> cin cols h4..h4+3 (col0 dead);
    //      sigma = relu(feat0) -> OUT4; SH -> cin cols 16..31 ----
    {
        bf16x8 a2[4][2];
        #pragma unroll
        for (int m = 0; m < 4; ++m)
            #pragma unroll
            for (int kk = 0; kk < 2; ++kk)
                a2[m][kk] = ldf64(ACT, w * 64 + m * 16 + q, kk * 32 + h8);
        {   // SH -> cols 16..31 of this wave's rows (after h reads above)
            int rayloc = w >> 1;
            bf16x8 shlo = *(const bf16x8*)(smem + OFF_SHB + rayloc * 32);
            bf16x8 shhi = *(const bf16x8*)(smem + OFF_SHB + rayloc * 32 + 16);
            int row = w * 64 + l;
            *(bf16x8*)(ACT + off128(row, 16)) = shlo;
            *(bf16x8*)(ACT + off128(row, 24)) = shhi;
        }
        #pragma unroll
        for (int m = 0; m < 4; ++m) {
            f32x4 acc = {0.f, 0.f, 0.f, 0.f};
            acc = __builtin_amdgcn_mfma_f32_16x16x32_bf16(bW1[0], a2[m][0], acc, 0, 0, 0);
            acc = __builtin_amdgcn_mfma_f32_16x16x32_bf16(bW1[1], a2[m][1], acc, 0, 0, 0);
            int s = w * 64 + m * 16 + q;
            *(ull*)(ACT + off128(s, h4)) = pk4(acc[0], acc[1], acc[2], acc[3]);  // raw dc (col0 dead)
            if (h4 == 0)
                *(unsigned short*)(smem + OFF_OUT4 + s * 8) = f2bf(fmaxf(acc[0], 0.f));
        }
    }

    // ---- GEMM3 (swapped): c1 = relu(cin @ Wc0perm^T), k=32, in-place cols 0..63 ----
    {
        bf16x8 a3[4];
        #pragma unroll
        for (int m = 0; m < 4; ++m) a3[m] = ldf64(ACT, w * 64 + m * 16 + q, h8);
        #pragma unroll
        for (int n = 0; n < 4; ++n) {
            bf16x8 bw = ldf32(smem + OFF_WC0, n * 16 + q, h8);
            #pragma unroll
            for (int m = 0; m < 4; ++m) {
                f32x4 acc = {0.f, 0.f, 0.f, 0.f};
                acc = __builtin_amdgcn_mfma_f32_16x16x32_bf16(bw, a3[m], acc, 0, 0, 0);
                *(ull*)(ACT + off128(w * 64 + m * 16 + q, n * 16 + h4)) = pk4r(acc);
            }
        }
    }

    // ---- GEMM4 (swapped): c2 = relu(c1 @ Wc1^T), k=64, in-place ----
    {
        bf16x8 a4[4][2];
        #pragma unroll
        for (int m = 0; m < 4; ++m)
            #pragma unroll
            for (int kk = 0; kk < 2; ++kk)
                a4[m][kk] = ldf64(ACT, w * 64 + m * 16 + q, kk * 32 + h8);
        #pragma unroll
        for (int n = 0; n < 4; ++n) {
            #pragma unroll
            for (int m = 0; m < 4; ++m) {
                f32x4 acc = {0.f, 0.f, 0.f, 0.f};
                acc = __builtin_amdgcn_mfma_f32_16x16x32_bf16(bWc1[n][0], a4[m][0], acc, 0, 0, 0);
                acc = __builtin_amdgcn_mfma_f32_16x16x32_bf16(bWc1[n][1], a4[m][1], acc, 0, 0, 0);
                *(ull*)(ACT + off128(w * 64 + m * 16 + q, n * 16 + h4)) = pk4r(acc);
            }
        }
    }

    // ---- GEMM5 (swapped): colors = c2 @ Wc2^T; h4==0 lanes hold (r,g,b) of sample q-block ----
    {
        bf16x8 a5[4][2];
        #pragma unroll
        for (int m = 0; m < 4; ++m)
            #pragma unroll
            for (int kk = 0; kk < 2; ++kk)
                a5[m][kk] = ldf64(ACT, w * 64 + m * 16 + q, kk * 32 + h8);
        #pragma unroll
        for (int m = 0; m < 4; ++m) {
            f32x4 acc = {0.f, 0.f, 0.f, 0.f};
            acc = __builtin_amdgcn_mfma_f32_16x16x32_bf16(bW2[0], a5[m][0], acc, 0, 0, 0);
            acc = __builtin_amdgcn_mfma_f32_16x16x32_bf16(bW2[1], a5[m][1], acc, 0, 0, 0);
            if (h4 == 0) {
                unsigned short* o = (unsigned short*)(smem + OFF_OUT4) + (w * 64 + m * 16 + q) * 4;
                o[1] = f2bf(acc[0]); o[2] = f2bf(acc[1]); o[3] = f2bf(acc[2]);
            }
        }
    }

    __syncthreads();   // ---- barrier 2 ----

    // ---- output: thread writes its own 4 consecutive slots (64B contiguous), f32 expand ----
    {
        const ull* o8 = (const ull*)(smem + OFF_OUT4);
        int ray = tid >> 7;
        float* op = out + ((size_t)b0 * 512 + tid * 4) * 4;
        int r = rank0;
        #pragma unroll
        for (int i = 0; i < 4; ++i) {
            float4 v = {0.f, 0.f, 0.f, 0.f};
            if (mb[i]) {
                ull pk = o8[ray * 128 + r];
                v.x = __uint_as_float((unsigned int)(pk & 0xFFFFull) << 16);
                v.y = __uint_as_float((unsigned int)((pk >> 16) & 0xFFFFull) << 16);
                v.z = __uint_as_float((unsigned int)((pk >> 32) & 0xFFFFull) << 16);
                v.w = __uint_as_float((unsigned int)(pk >> 48) << 16);
                r++;
            }
            *(float4*)(op + i * 4) = v;
        }
    }
}

extern "C" void kernel_launch(void* const* d_in, const int* in_sizes, int n_in,
                              void* d_out, int out_size, void* d_ws, size_t ws_size,
                              hipStream_t stream) {
    const float* df   = (const float*)d_in[0];
    const void*  mk   = d_in[1];
    const float* rays = (const float*)d_in[2];
    const float* Ws0  = (const float*)d_in[3];
    const float* Ws1  = (const float*)d_in[4];
    const float* Wc0  = (const float*)d_in[5];
    const float* Wc1  = (const float*)d_in[6];
    const float* Wc2  = (const float*)d_in[7];
    float* out = (float*)d_out;
    int* flag = (int*)d_ws;

    int B = in_sizes[2] / 3;   // 8192 rays
    detect_mask_kernel<<<1, 64, 0, stream>>>((const int*)mk, flag);
    nnrender_main<<<B / 2, 256, 0, stream>>>(df, mk, rays, Ws0, Ws1, Wc0, Wc1, Wc2, out, flag);
}

// Round 5
// 292.098 us; speedup vs baseline: 1.2332x; 1.2332x over previous
//
#include <hip/hip_runtime.h>
#include <stdint.h>

typedef __attribute__((ext_vector_type(8))) short bf16x8;
typedef __attribute__((ext_vector_type(4))) float f32x4;
typedef unsigned long long ull;

// ---- LDS layout (bytes), total 53328 -> 3 blocks/CU @ 512 thr = 24 waves/CU ----
#define OFF_ACT  0        // [256][64] bf16, stride 128B, swz off128()  (h / cin / c1 / c2)
#define OFF_W0   32768    // [64][32] bf16, stride 64B  (Ws0)
#define OFF_WC0  36864    // [64][32] bf16 (k-permuted: col0 dead, 1..15=dc, 16..31=SH)
#define OFF_WC1  40960    // [64][64] bf16, stride 128B, swz off128()
#define OFF_OUT4 49152    // [256][4] f32  (sigma, r, g, b)
#define OFF_SHB  53248    // [2][16] u16 (bf16 SH coeffs)
#define OFF_WTOT 53312    // [4] int
#define SMEM_BYTES 53328

__device__ __forceinline__ unsigned short f2bf(float f) {
    unsigned int u = __float_as_uint(f);
    unsigned int r = (u + 0x7FFFu + ((u >> 16) & 1u)) >> 16;   // RNE
    return (unsigned short)r;
}

__device__ __forceinline__ bf16x8 pack8(float4 a, float4 b) {
    bf16x8 r;
    r[0] = (short)f2bf(a.x); r[1] = (short)f2bf(a.y);
    r[2] = (short)f2bf(a.z); r[3] = (short)f2bf(a.w);
    r[4] = (short)f2bf(b.x); r[5] = (short)f2bf(b.y);
    r[6] = (short)f2bf(b.z); r[7] = (short)f2bf(b.w);
    return r;
}

__device__ __forceinline__ ull pk4(float a, float b, float c, float d) {
    return (ull)f2bf(a) | ((ull)f2bf(b) << 16) | ((ull)f2bf(c) << 32) | ((ull)f2bf(d) << 48);
}
__device__ __forceinline__ ull pk4r(f32x4 v) {  // relu + pack
    return pk4(fmaxf(v[0], 0.f), fmaxf(v[1], 0.f), fmaxf(v[2], 0.f), fmaxf(v[3], 0.f));
}

// 128B-stride tiles (ACT/WC1): slot = (row&7) ^ (bit3(row)<<1)
//  - b128 reads (16 rows, fixed col): 2-way -> free
//  - b64 D-writes: residual 4-way (accepted, ~3% runtime)
__device__ __forceinline__ int off128(int row, int col) {
    int off = row * 128 + col * 2;
    return off ^ ((((row & 7) ^ ((row >> 2) & 2))) << 4);
}
// 64B-stride tiles (W0/WC0): ^(((row>>1)&3)<<4) -> <=2-way (free)
__device__ __forceinline__ bf16x8 ldf32(const char* base, int row, int k0) {
    int off = row * 64 + k0 * 2;
    off ^= ((row >> 1) & 3) << 4;
    return *(const bf16x8*)(base + off);
}
__device__ __forceinline__ bf16x8 ldf64(const char* base, int row, int k0) {
    return *(const bf16x8*)(base + off128(row, k0));
}

// Probe: mask int32 vs bool bytes (ray 0 has exactly 128 valid).
__global__ void __launch_bounds__(64) detect_mask_kernel(const int* __restrict__ m, int* __restrict__ flag) {
    int l = threadIdx.x;
    unsigned long long s = 0;
    #pragma unroll
    for (int i = 0; i < 8; ++i) s += (unsigned long long)(unsigned int)m[l + i * 64];
    #pragma unroll
    for (int d = 32; d >= 1; d >>= 1) s += __shfl_down(s, d, 64);
    if (l == 0) *flag = (s == 128ull) ? 1 : 0;
}

__global__ void __launch_bounds__(512, 6) nnrender_main(
    const float* __restrict__ df, const void* __restrict__ maskp, const float* __restrict__ rays,
    const float* __restrict__ Ws0, const float* __restrict__ Ws1, const float* __restrict__ Wc0,
    const float* __restrict__ Wc1, const float* __restrict__ Wc2,
    float* __restrict__ out, const int* __restrict__ flagp) {

    __shared__ __align__(16) char smem[SMEM_BYTES];
    const int tid = threadIdx.x;
    const int w = tid >> 6;           // wave 0..7, owns sample rows [32w, 32w+32)
    const int l = tid & 63;
    const int q = l & 15;
    const int h8 = (l >> 4) << 3;     // k-chunk base
    const int h4 = (l >> 4) << 2;     // D feature-group base (swapped layout)
    const int blk = blockIdx.x;
    const int b0 = blk * 2;

    char* ACT = smem + OFF_ACT;
    const int use_i32 = *flagp;

    // ---- phase 0 ----
    // df B-frags: 2 m-groups of 16 rows each (wave-contiguous 2KB segments)
    bf16x8 dfr[2];
    {
        const float* p0 = df + ((size_t)(blk * 256 + w * 32 + q)) * 32 + h8;
        #pragma unroll
        for (int m = 0; m < 2; ++m) {
            const float* p = p0 + m * 16 * 32;
            dfr[m] = pack8(*(const float4*)p, *(const float4*)(p + 4));
        }
    }
    // W1/W2 A-frags in registers (small; used twice each)
    bf16x8 bW1[2], bW2[2];
    {
        const float* p1 = Ws1 + q * 64 + h8;
        bW1[0] = pack8(*(const float4*)p1, *(const float4*)(p1 + 4));
        bW1[1] = pack8(*(const float4*)(p1 + 32), *(const float4*)(p1 + 36));
        int qc = (q < 3) ? q : 0;
        const float* p2 = Wc2 + qc * 64 + h8;
        bW2[0] = pack8(*(const float4*)p2, *(const float4*)(p2 + 4));
        bW2[1] = pack8(*(const float4*)(p2 + 32), *(const float4*)(p2 + 36));
    }

    // mask load + wave scan (scan waves 0..3 cover the 2 rays' 1024 slots)
    unsigned int mb[4] = {0, 0, 0, 0};
    int c = 0, incl = 0;
    if (tid < 256) {
        size_t base = (size_t)b0 * 512 + tid * 4;
        if (use_i32) {
            int4 mv = *(const int4*)((const int*)maskp + base);
            mb[0] = mv.x != 0; mb[1] = mv.y != 0; mb[2] = mv.z != 0; mb[3] = mv.w != 0;
        } else {
            unsigned int u = *(const unsigned int*)((const unsigned char*)maskp + base);
            mb[0] = (u & 0xFFu) != 0; mb[1] = ((u >> 8) & 0xFFu) != 0;
            mb[2] = ((u >> 16) & 0xFFu) != 0; mb[3] = (u >> 24) != 0;
        }
        c = (int)(mb[0] + mb[1] + mb[2] + mb[3]);
        incl = c;
        #pragma unroll
        for (int d = 1; d < 64; d <<= 1) {
            int v = __shfl_up(incl, d, 64);
            if (l >= d) incl += v;
        }
        if (l == 63) ((int*)(smem + OFF_WTOT))[w] = incl;
    }

    // stage W0 / WC0perm (scalar, 64B-stride swizzle)
    for (int i = tid; i < 2048; i += 512) {
        int n = i >> 5, k = i & 31;
        int off = i * 2 ^ (((n >> 1) & 3) << 4);
        *(unsigned short*)(smem + OFF_W0 + off) = f2bf(Ws0[n * 32 + k]);
        float v;
        if (k == 0) v = 0.f;
        else if (k < 16) v = Wc0[n * 31 + 15 + k];   // dc cols 1..15
        else v = Wc0[n * 31 + (k - 16)];             // SH cols 16..31
        *(unsigned short*)(smem + OFF_WC0 + off) = f2bf(v);
    }
    // stage WC1 (float4 -> packed 4x bf16 u64 store)
    #pragma unroll
    for (int it = 0; it < 2; ++it) {
        int idx = (tid + it * 512) * 4;          // element index, k multiple of 4
        int n = idx >> 6, k = idx & 63;
        float4 v = *(const float4*)(Wc1 + n * 64 + k);
        *(ull*)(smem + OFF_WC1 + off128(n, k)) = pk4(v.x, v.y, v.z, v.w);
    }

    if (tid < 2) {  // SH deg-4 (16 coeffs) for this block's 2 rays
        const float* rd = rays + (size_t)(b0 + tid) * 3;
        float x = rd[0], y = rd[1], z = rd[2];
        float x2 = x * x, y2 = y * y, z2 = z * z, xy = x * y, yz = y * z, xz = x * z;
        float s[16];
        s[0] = 0.28209479177387814f;
        s[1] = -0.48860251190291987f * y;
        s[2] =  0.48860251190291987f * z;
        s[3] = -0.48860251190291987f * x;
        s[4] =  1.0925484305920792f * xy;
        s[5] = -1.0925484305920792f * yz;
        s[6] =  0.94617469575755997f * z2 - 0.31539156525251999f;
        s[7] = -1.0925484305920792f * xz;
        s[8] =  0.54627421529603959f * (x2 - y2);
        s[9] =  0.59004358992664352f * y * (-3.0f * x2 + y2);
        s[10] = 2.8906114426405538f * xy * z;
        s[11] = 0.45704579946446572f * y * (1.0f - 5.0f * z2);
        s[12] = 0.3731763325901154f * z * (5.0f * z2 - 3.0f);
        s[13] = 0.45704579946446572f * x * (1.0f - 5.0f * z2);
        s[14] = 1.445305721320277f * z * (x2 - y2);
        s[15] = 0.59004358992664352f * x * (-x2 + 3.0f * y2);
        unsigned short* d = (unsigned short*)(smem + OFF_SHB) + tid * 16;
        #pragma unroll
        for (int i = 0; i < 16; ++i) d[i] = f2bf(s[i]);
    }

    __syncthreads();   // ---- barrier 1 ----

    int rank0 = 0;
    if (tid < 256) {
        int base = (w & 1) ? ((int*)(smem + OFF_WTOT))[w - 1] : 0;
        rank0 = base + incl - c;
    }

    // ---- GEMM1 (swapped): h feats; lane -> feats n*16+h4..+3 of sample 32w+m*16+q ----
    #pragma unroll
    for (int n = 0; n < 4; ++n) {
        bf16x8 bw = ldf32(smem + OFF_W0, n * 16 + q, h8);
        #pragma unroll
        for (int m = 0; m < 2; ++m) {
            f32x4 acc = {0.f, 0.f, 0.f, 0.f};
            acc = __builtin_amdgcn_mfma_f32_16x16x32_bf16(bw, dfr[m], acc, 0, 0, 0);
            *(ull*)(ACT + off128(w * 32 + m * 16 + q, n * 16 + h4)) = pk4r(acc);
        }
    }

    // ---- GEMM2 (swapped): dc feats -> cin cols 0..15 (col0 dead); sigma -> OUT4; SH -> cols 16..31 ----
    {
        bf16x8 a2[2][2];
        #pragma unroll
        for (int m = 0; m < 2; ++m)
            #pragma unroll
            for (int kk = 0; kk < 2; ++kk)
                a2[m][kk] = ldf64(ACT, w * 32 + m * 16 + q, kk * 32 + h8);
        if (l < 32) {   // SH -> cols 16..31 of this wave's 32 rows (reads above precede, in-order DS)
            int rayloc = w >> 2;
            bf16x8 shlo = *(const bf16x8*)(smem + OFF_SHB + rayloc * 32);
            bf16x8 shhi = *(const bf16x8*)(smem + OFF_SHB + rayloc * 32 + 16);
            int row = w * 32 + l;
            *(bf16x8*)(ACT + off128(row, 16)) = shlo;
            *(bf16x8*)(ACT + off128(row, 24)) = shhi;
        }
        #pragma unroll
        for (int m = 0; m < 2; ++m) {
            f32x4 acc = {0.f, 0.f, 0.f, 0.f};
            acc = __builtin_amdgcn_mfma_f32_16x16x32_bf16(bW1[0], a2[m][0], acc, 0, 0, 0);
            acc = __builtin_amdgcn_mfma_f32_16x16x32_bf16(bW1[1], a2[m][1], acc, 0, 0, 0);
            int s = w * 32 + m * 16 + q;
            *(ull*)(ACT + off128(s, h4)) = pk4(acc[0], acc[1], acc[2], acc[3]);  // raw dc
            if (h4 == 0)
                ((float*)(smem + OFF_OUT4))[s * 4] = fmaxf(acc[0], 0.f);         // sigma
        }
    }

    // ---- GEMM3 (swapped): c1 = relu(cin @ Wc0perm^T), k=32, in-place ----
    {
        bf16x8 a3[2];
        #pragma unroll
        for (int m = 0; m < 2; ++m) a3[m] = ldf64(ACT, w * 32 + m * 16 + q, h8);
        #pragma unroll
        for (int n = 0; n < 4; ++n) {
            bf16x8 bw = ldf32(smem + OFF_WC0, n * 16 + q, h8);
            #pragma unroll
            for (int m = 0; m < 2; ++m) {
                f32x4 acc = {0.f, 0.f, 0.f, 0.f};
                acc = __builtin_amdgcn_mfma_f32_16x16x32_bf16(bw, a3[m], acc, 0, 0, 0);
                *(ull*)(ACT + off128(w * 32 + m * 16 + q, n * 16 + h4)) = pk4r(acc);
            }
        }
    }

    // ---- GEMM4 (swapped): c2 = relu(c1 @ Wc1^T), k=64, in-place ----
    {
        bf16x8 a4[2][2];
        #pragma unroll
        for (int m = 0; m < 2; ++m)
            #pragma unroll
            for (int kk = 0; kk < 2; ++kk)
                a4[m][kk] = ldf64(ACT, w * 32 + m * 16 + q, kk * 32 + h8);
        #pragma unroll
        for (int n = 0; n < 4; ++n) {
            bf16x8 bA = ldf64(smem + OFF_WC1, n * 16 + q, h8);
            bf16x8 bB = ldf64(smem + OFF_WC1, n * 16 + q, 32 + h8);
            #pragma unroll
            for (int m = 0; m < 2; ++m) {
                f32x4 acc = {0.f, 0.f, 0.f, 0.f};
                acc = __builtin_amdgcn_mfma_f32_16x16x32_bf16(bA, a4[m][0], acc, 0, 0, 0);
                acc = __builtin_amdgcn_mfma_f32_16x16x32_bf16(bB, a4[m][1], acc, 0, 0, 0);
                *(ull*)(ACT + off128(w * 32 + m * 16 + q, n * 16 + h4)) = pk4r(acc);
            }
        }
    }

    // ---- GEMM5 (swapped): colors; h4==0 lanes hold (r,g,b) of sample ----
    {
        bf16x8 a5[2][2];
        #pragma unroll
        for (int m = 0; m < 2; ++m)
            #pragma unroll
            for (int kk = 0; kk < 2; ++kk)
                a5[m][kk] = ldf64(ACT, w * 32 + m * 16 + q, kk * 32 + h8);
        #pragma unroll
        for (int m = 0; m < 2; ++m) {
            f32x4 acc = {0.f, 0.f, 0.f, 0.f};
            acc = __builtin_amdgcn_mfma_f32_16x16x32_bf16(bW2[0], a5[m][0], acc, 0, 0, 0);
            acc = __builtin_amdgcn_mfma_f32_16x16x32_bf16(bW2[1], a5[m][1], acc, 0, 0, 0);
            if (h4 == 0) {
                float* o = (float*)(smem + OFF_OUT4) + (w * 32 + m * 16 + q) * 4;
                o[1] = acc[0]; o[2] = acc[1]; o[3] = acc[2];
            }
        }
    }

    __syncthreads();   // ---- barrier 2 ----

    // ---- output (tid<256): 4 consecutive slots = 64B contiguous per thread (R3-proven pattern) ----
    if (tid < 256) {
        const float4* o4 = (const float4*)(smem + OFF_OUT4);
        int ray = tid >> 7;
        float* op = out + ((size_t)b0 * 512 + tid * 4) * 4;
        int r = rank0;
        #pragma unroll
        for (int i = 0; i < 4; ++i) {
            float4 v = {0.f, 0.f, 0.f, 0.f};
            if (mb[i]) { v = o4[ray * 128 + r]; r++; }
            *(float4*)(op + i * 4) = v;
        }
    }
}

extern "C" void kernel_launch(void* const* d_in, const int* in_sizes, int n_in,
                              void* d_out, int out_size, void* d_ws, size_t ws_size,
                              hipStream_t stream) {
    const float* df   = (const float*)d_in[0];
    const void*  mk   = d_in[1];
    const float* rays = (const float*)d_in[2];
    const float* Ws0  = (const float*)d_in[3];
    const float* Ws1  = (const float*)d_in[4];
    const float* Wc0  = (const float*)d_in[5];
    const float* Wc1  = (const float*)d_in[6];
    const float* Wc2  = (const float*)d_in[7];
    float* out = (float*)d_out;
    int* flag = (int*)d_ws;

    int B = in_sizes[2] / 3;   // 8192 rays
    detect_mask_kernel<<<1, 64, 0, stream>>>((const int*)mk, flag);
    nnrender_main<<<B / 2, 512, 0, stream>>>(df, mk, rays, Ws0, Ws1, Wc0, Wc1, Wc2, out, flag);
}

// Round 6
// 253.347 us; speedup vs baseline: 1.4218x; 1.1530x over previous
//
#include <hip/hip_runtime.h>
#include <stdint.h>

typedef __attribute__((ext_vector_type(8))) short bf16x8;
typedef __attribute__((ext_vector_type(4))) float f32x4;
typedef __attribute__((ext_vector_type(8))) float f32x8;
typedef __attribute__((ext_vector_type(4))) __bf16 b16x4;
typedef __attribute__((ext_vector_type(8))) __bf16 b16x8v;
typedef unsigned long long ull;

// ---- LDS layout (bytes), total 53328 -> 3 blocks/CU @ 512 thr = 24 waves/CU ----
#define OFF_ACT  0        // [256][64] bf16, stride 128B, swz off128()  (h / cin / c1 / c2)
#define OFF_W0   32768    // [64][32] bf16, 64B-row swizzle  (Ws0 image)
#define OFF_WC0  36864    // [64][32] bf16 (k-permuted: col0 dead, 1..15=dc, 16..31=SH)
#define OFF_WC1  40960    // [64][64] bf16, off128 swizzle
#define OFF_OUT4 49152    // [256][4] f32  (sigma, r, g, b)
#define OFF_SHB  53248    // [2][16] u16 (bf16 SH coeffs)
#define OFF_WTOT 53312    // [4] int
#define SMEM_BYTES 53328

// ws scratch layout: [0] int flag (mask i32?), [256..] weight images (20KB)
#define WSI_W0    0        // 4096B  W0 LDS image (linear copy target)
#define WSI_WC0   4096     // 4096B  WC0perm image
#define WSI_WC1   8192     // 8192B  WC1 image
#define WSI_W1F   16384    // 2048B  per-lane Ws1 fragments (lane*32B)
#define WSI_W2F   18432    // 2048B  per-lane Wc2 fragments

__device__ __forceinline__ unsigned short f2bf(float f) {   // cold paths only
    unsigned int u = __float_as_uint(f);
    return (unsigned short)((u + 0x7FFFu + ((u >> 16) & 1u)) >> 16);
}

// hot converters: compile to v_cvt_pk_bf16_f32 (RNE)
__device__ __forceinline__ bf16x8 pack8v(float4 a, float4 b) {
    f32x8 v = {a.x, a.y, a.z, a.w, b.x, b.y, b.z, b.w};
    b16x8v c = __builtin_convertvector(v, b16x8v);
    return __builtin_bit_cast(bf16x8, c);
}
__device__ __forceinline__ ull pk4(f32x4 v) {
    b16x4 c = __builtin_convertvector(v, b16x4);
    return __builtin_bit_cast(ull, c);
}
__device__ __forceinline__ ull pk4r(f32x4 v) {
    f32x4 z = {fmaxf(v[0], 0.f), fmaxf(v[1], 0.f), fmaxf(v[2], 0.f), fmaxf(v[3], 0.f)};
    return pk4(z);
}

// 128B-stride tiles (ACT/WC1): slot = (row&7) ^ (bit3(row)<<1)
__device__ __forceinline__ int off128(int row, int col) {
    int off = row * 128 + col * 2;
    return off ^ ((((row & 7) ^ ((row >> 2) & 2))) << 4);
}
// 64B-stride tiles (W0/WC0): ^(((row>>1)&3)<<4)
__device__ __forceinline__ bf16x8 ldf32(const char* base, int row, int k0) {
    int off = row * 64 + k0 * 2;
    off ^= ((row >> 1) & 3) << 4;
    return *(const bf16x8*)(base + off);
}
__device__ __forceinline__ bf16x8 ldf64(const char* base, int row, int k0) {
    return *(const bf16x8*)(base + off128(row, k0));
}

// ---- prep: mask-dtype probe + bf16 pre-swizzled weight images into ws ----
__global__ void __launch_bounds__(256) prep_kernel(
    const int* __restrict__ mk, const float* __restrict__ Ws0, const float* __restrict__ Ws1,
    const float* __restrict__ Wc0, const float* __restrict__ Wc1, const float* __restrict__ Wc2,
    char* __restrict__ ws) {
    int tid = threadIdx.x;
    if (tid < 64) {   // ray 0 has exactly 128 valid -> sum of first 512 i32 words == 128 iff i32
        unsigned long long s = 0;
        #pragma unroll
        for (int i = 0; i < 8; ++i) s += (unsigned long long)(unsigned int)mk[tid + i * 64];
        #pragma unroll
        for (int d = 32; d >= 1; d >>= 1) s += __shfl_down(s, d, 64);
        if (tid == 0) *(int*)ws = (s == 128ull) ? 1 : 0;
    }
    char* img = ws + 256;
    for (int i = tid; i < 2048; i += 256) {          // W0 + WC0perm images
        int n = i >> 5, k = i & 31;
        int off = (i * 2) ^ (((n >> 1) & 3) << 4);
        *(unsigned short*)(img + WSI_W0 + off) = f2bf(Ws0[n * 32 + k]);
        float v;
        if (k == 0) v = 0.f;
        else if (k < 16) v = Wc0[n * 31 + 15 + k];   // dc cols 1..15
        else v = Wc0[n * 31 + (k - 16)];             // SH cols 16..31
        *(unsigned short*)(img + WSI_WC0 + off) = f2bf(v);
    }
    for (int i = tid; i < 4096; i += 256) {          // WC1 image
        int n = i >> 6, k = i & 63;
        *(unsigned short*)(img + WSI_WC1 + off128(n, k)) = f2bf(Wc1[n * 64 + k]);
    }
    for (int i = tid; i < 1024; i += 256) {          // per-lane W1 / W2 fragments
        int l = i >> 4, e = i & 15;
        int q = l & 15, h8 = (l >> 4) << 3;
        int k = (e < 8) ? (h8 + e) : (32 + h8 + (e - 8));
        *(unsigned short*)(img + WSI_W1F + l * 32 + e * 2) = f2bf(Ws1[q * 64 + k]);
        int qc = (q < 3) ? q : 0;
        *(unsigned short*)(img + WSI_W2F + l * 32 + e * 2) = f2bf(Wc2[qc * 64 + k]);
    }
}

__global__ void __launch_bounds__(512, 6) nnrender_main(
    const float* __restrict__ df, const void* __restrict__ maskp, const float* __restrict__ rays,
    float* __restrict__ out, const char* __restrict__ ws) {

    __shared__ __align__(16) char smem[SMEM_BYTES];
    const int tid = threadIdx.x;
    const int w = tid >> 6;           // wave 0..7, owns sample rows [32w, 32w+32)
    const int l = tid & 63;
    const int q = l & 15;
    const int h8 = (l >> 4) << 3;     // k-chunk base
    const int h4 = (l >> 4) << 2;     // D feature-group base (swapped layout)
    const int blk = blockIdx.x;
    const int b0 = blk * 2;

    char* ACT = smem + OFF_ACT;
    const int use_i32 = *(const int*)ws;
    const char* wsimg = ws + 256;

    // ---- phase 0 ----
    // df B-frags: 2 m-groups (wave-contiguous 2KB segments), cvt_pk conversion
    bf16x8 dfr[2];
    {
        const float* p0 = df + ((size_t)(blk * 256 + w * 32 + q)) * 32 + h8;
        #pragma unroll
        for (int m = 0; m < 2; ++m) {
            const float* p = p0 + m * 16 * 32;
            dfr[m] = pack8v(*(const float4*)p, *(const float4*)(p + 4));
        }
    }
    // W1/W2 fragments: direct bf16 loads from prepped image (no conversion)
    bf16x8 bW1[2], bW2[2];
    {
        const char* f1 = wsimg + WSI_W1F + l * 32;
        bW1[0] = *(const bf16x8*)f1; bW1[1] = *(const bf16x8*)(f1 + 16);
        const char* f2 = wsimg + WSI_W2F + l * 32;
        bW2[0] = *(const bf16x8*)f2; bW2[1] = *(const bf16x8*)(f2 + 16);
    }
    // stage 16KB weight image ws->LDS (linear, already bf16+swizzled)
    {
        const uint4* wsrc = (const uint4*)(wsimg);
        uint4* wdst = (uint4*)(smem + OFF_W0);
        wdst[tid] = wsrc[tid];
        wdst[tid + 512] = wsrc[tid + 512];
    }

    // mask load + wave scan (waves 0..3 cover the 2 rays' 1024 slots)
    unsigned int mb[4] = {0, 0, 0, 0};
    int c = 0, incl = 0;
    if (tid < 256) {
        size_t base = (size_t)b0 * 512 + tid * 4;
        if (use_i32) {
            int4 mv = *(const int4*)((const int*)maskp + base);
            mb[0] = mv.x != 0; mb[1] = mv.y != 0; mb[2] = mv.z != 0; mb[3] = mv.w != 0;
        } else {
            unsigned int u = *(const unsigned int*)((const unsigned char*)maskp + base);
            mb[0] = (u & 0xFFu) != 0; mb[1] = ((u >> 8) & 0xFFu) != 0;
            mb[2] = ((u >> 16) & 0xFFu) != 0; mb[3] = (u >> 24) != 0;
        }
        c = (int)(mb[0] + mb[1] + mb[2] + mb[3]);
        incl = c;
        #pragma unroll
        for (int d = 1; d < 64; d <<= 1) {
            int v = __shfl_up(incl, d, 64);
            if (l >= d) incl += v;
        }
        if (l == 63) ((int*)(smem + OFF_WTOT))[w] = incl;
    }

    if (tid < 2) {  // SH deg-4 (16 coeffs) for this block's 2 rays
        const float* rd = rays + (size_t)(b0 + tid) * 3;
        float x = rd[0], y = rd[1], z = rd[2];
        float x2 = x * x, y2 = y * y, z2 = z * z, xy = x * y, yz = y * z, xz = x * z;
        float s[16];
        s[0] = 0.28209479177387814f;
        s[1] = -0.48860251190291987f * y;
        s[2] =  0.48860251190291987f * z;
        s[3] = -0.48860251190291987f * x;
        s[4] =  1.0925484305920792f * xy;
        s[5] = -1.0925484305920792f * yz;
        s[6] =  0.94617469575755997f * z2 - 0.31539156525251999f;
        s[7] = -1.0925484305920792f * xz;
        s[8] =  0.54627421529603959f * (x2 - y2);
        s[9] =  0.59004358992664352f * y * (-3.0f * x2 + y2);
        s[10] = 2.8906114426405538f * xy * z;
        s[11] = 0.45704579946446572f * y * (1.0f - 5.0f * z2);
        s[12] = 0.3731763325901154f * z * (5.0f * z2 - 3.0f);
        s[13] = 0.45704579946446572f * x * (1.0f - 5.0f * z2);
        s[14] = 1.445305721320277f * z * (x2 - y2);
        s[15] = 0.59004358992664352f * x * (-x2 + 3.0f * y2);
        unsigned short* d = (unsigned short*)(smem + OFF_SHB) + tid * 16;
        #pragma unroll
        for (int i = 0; i < 16; ++i) d[i] = f2bf(s[i]);
    }

    __syncthreads();   // ---- barrier 1 ----

    int rank0 = 0;
    if (tid < 256) {
        int base = (w & 1) ? ((int*)(smem + OFF_WTOT))[w - 1] : 0;
        rank0 = base + incl - c;
    }

    // ---- GEMM1 (swapped): h feats; lane -> feats n*16+h4..+3 of sample 32w+m*16+q ----
    #pragma unroll
    for (int n = 0; n < 4; ++n) {
        bf16x8 bw = ldf32(smem + OFF_W0, n * 16 + q, h8);
        #pragma unroll
        for (int m = 0; m < 2; ++m) {
            f32x4 acc = {0.f, 0.f, 0.f, 0.f};
            acc = __builtin_amdgcn_mfma_f32_16x16x32_bf16(bw, dfr[m], acc, 0, 0, 0);
            *(ull*)(ACT + off128(w * 32 + m * 16 + q, n * 16 + h4)) = pk4r(acc);
        }
    }

    // ---- GEMM2 (swapped): dc feats -> cin cols 0..15 (col0 dead); sigma -> OUT4; SH -> cols 16..31 ----
    {
        bf16x8 a2[2][2];
        #pragma unroll
        for (int m = 0; m < 2; ++m)
            #pragma unroll
            for (int kk = 0; kk < 2; ++kk)
                a2[m][kk] = ldf64(ACT, w * 32 + m * 16 + q, kk * 32 + h8);
        if (l < 32) {   // SH -> cols 16..31 of this wave's 32 rows (reads above precede, in-order DS)
            int rayloc = w >> 2;
            bf16x8 shlo = *(const bf16x8*)(smem + OFF_SHB + rayloc * 32);
            bf16x8 shhi = *(const bf16x8*)(smem + OFF_SHB + rayloc * 32 + 16);
            int row = w * 32 + l;
            *(bf16x8*)(ACT + off128(row, 16)) = shlo;
            *(bf16x8*)(ACT + off128(row, 24)) = shhi;
        }
        #pragma unroll
        for (int m = 0; m < 2; ++m) {
            f32x4 acc = {0.f, 0.f, 0.f, 0.f};
            acc = __builtin_amdgcn_mfma_f32_16x16x32_bf16(bW1[0], a2[m][0], acc, 0, 0, 0);
            acc = __builtin_amdgcn_mfma_f32_16x16x32_bf16(bW1[1], a2[m][1], acc, 0, 0, 0);
            int s = w * 32 + m * 16 + q;
            *(ull*)(ACT + off128(s, h4)) = pk4(acc);   // raw dc (col0 dead)
            if (h4 == 0)
                ((float*)(smem + OFF_OUT4))[s * 4] = fmaxf(acc[0], 0.f);   // sigma
        }
    }

    // ---- GEMM3 (swapped): c1 = relu(cin @ Wc0perm^T), k=32, in-place ----
    {
        bf16x8 a3[2];
        #pragma unroll
        for (int m = 0; m < 2; ++m) a3[m] = ldf64(ACT, w * 32 + m * 16 + q, h8);
        #pragma unroll
        for (int n = 0; n < 4; ++n) {
            bf16x8 bw = ldf32(smem + OFF_WC0, n * 16 + q, h8);
            #pragma unroll
            for (int m = 0; m < 2; ++m) {
                f32x4 acc = {0.f, 0.f, 0.f, 0.f};
                acc = __builtin_amdgcn_mfma_f32_16x16x32_bf16(bw, a3[m], acc, 0, 0, 0);
                *(ull*)(ACT + off128(w * 32 + m * 16 + q, n * 16 + h4)) = pk4r(acc);
            }
        }
    }

    // ---- GEMM4 (swapped): c2 = relu(c1 @ Wc1^T), k=64, in-place ----
    {
        bf16x8 a4[2][2];
        #pragma unroll
        for (int m = 0; m < 2; ++m)
            #pragma unroll
            for (int kk = 0; kk < 2; ++kk)
                a4[m][kk] = ldf64(ACT, w * 32 + m * 16 + q, kk * 32 + h8);
        #pragma unroll
        for (int n = 0; n < 4; ++n) {
            bf16x8 bA = ldf64(smem + OFF_WC1, n * 16 + q, h8);
            bf16x8 bB = ldf64(smem + OFF_WC1, n * 16 + q, 32 + h8);
            #pragma unroll
            for (int m = 0; m < 2; ++m) {
                f32x4 acc = {0.f, 0.f, 0.f, 0.f};
                acc = __builtin_amdgcn_mfma_f32_16x16x32_bf16(bA, a4[m][0], acc, 0, 0, 0);
                acc = __builtin_amdgcn_mfma_f32_16x16x32_bf16(bB, a4[m][1], acc, 0, 0, 0);
                *(ull*)(ACT + off128(w * 32 + m * 16 + q, n * 16 + h4)) = pk4r(acc);
            }
        }
    }

    // ---- GEMM5 (swapped): colors; h4==0 lanes hold (r,g,b) of sample ----
    {
        bf16x8 a5[2][2];
        #pragma unroll
        for (int m = 0; m < 2; ++m)
            #pragma unroll
            for (int kk = 0; kk < 2; ++kk)
                a5[m][kk] = ldf64(ACT, w * 32 + m * 16 + q, kk * 32 + h8);
        #pragma unroll
        for (int m = 0; m < 2; ++m) {
            f32x4 acc = {0.f, 0.f, 0.f, 0.f};
            acc = __builtin_amdgcn_mfma_f32_16x16x32_bf16(bW2[0], a5[m][0], acc, 0, 0, 0);
            acc = __builtin_amdgcn_mfma_f32_16x16x32_bf16(bW2[1], a5[m][1], acc, 0, 0, 0);
            if (h4 == 0) {
                float* o = (float*)(smem + OFF_OUT4) + (w * 32 + m * 16 + q) * 4;
                o[1] = acc[0]; o[2] = acc[1]; o[3] = acc[2];
            }
        }
    }

    __syncthreads();   // ---- barrier 2 ----

    // ---- output (tid<256): 4 consecutive slots = 64B contiguous per thread ----
    if (tid < 256) {
        const float4* o4 = (const float4*)(smem + OFF_OUT4);
        int ray = tid >> 7;
        float* op = out + ((size_t)b0 * 512 + tid * 4) * 4;
        int r = rank0;
        #pragma unroll
        for (int i = 0; i < 4; ++i) {
            float4 v = {0.f, 0.f, 0.f, 0.f};
            if (mb[i]) { v = o4[ray * 128 + r]; r++; }
            *(float4*)(op + i * 4) = v;
        }
    }
}

extern "C" void kernel_launch(void* const* d_in, const int* in_sizes, int n_in,
                              void* d_out, int out_size, void* d_ws, size_t ws_size,
                              hipStream_t stream) {
    const float* df   = (const float*)d_in[0];
    const void*  mk   = d_in[1];
    const float* rays = (const float*)d_in[2];
    const float* Ws0  = (const float*)d_in[3];
    const float* Ws1  = (const float*)d_in[4];
    const float* Wc0  = (const float*)d_in[5];
    const float* Wc1  = (const float*)d_in[6];
    const float* Wc2  = (const float*)d_in[7];
    float* out = (float*)d_out;
    char* ws = (char*)d_ws;

    int B = in_sizes[2] / 3;   // 8192 rays
    prep_kernel<<<1, 256, 0, stream>>>((const int*)mk, Ws0, Ws1, Wc0, Wc1, Wc2, ws);
    nnrender_main<<<B / 2, 512, 0, stream>>>(df, mk, rays, out, ws);
}